// Round 12
// baseline (269.739 us; speedup 1.0000x reference)
//
#include <hip/hip_runtime.h>
#include <hip/hip_bf16.h>

#define BATCH 1024
#define SEQ 256
#define HIDDEN 128
#define VOCAB 60
#define ASTRIDE 136        // f16: 128 + 8 pad
#define EWSTRIDE 132       // f16: 66 dw == 2 mod 32 spreads random-token gathers

typedef _Float16 f16x8 __attribute__((ext_vector_type(8)));
typedef _Float16 f16x4 __attribute__((ext_vector_type(4)));
typedef float f32x4 __attribute__((ext_vector_type(4)));

__device__ __forceinline__ float fast_tanh(float x) {
    // tanh(x) = 1 - 2/(exp(2x)+1); exp(2x)=exp2(x*2*log2e). Branch-free, exact +-1 tails.
    float e = __builtin_amdgcn_exp2f(x * 2.8853900817779268f);
    return __builtin_fmaf(-2.0f, __builtin_amdgcn_rcpf(e + 1.0f), 1.0f);
}

// embW[v][i] = sum_j emb[v][j] * W_ih[i][j]  (fp32-exact input-projection table)
__global__ void rnn_prep_embw(const float* __restrict__ emb,
                              const float* __restrict__ W_ih,
                              float* __restrict__ embW) {
    const int v = blockIdx.x;
    const int i = threadIdx.x;
    __shared__ __align__(16) float e[HIDDEN];
    e[i] = emb[v * HIDDEN + i];
    __syncthreads();
    const float4* wrow = (const float4*)(W_ih + i * HIDDEN);
    const float4* e4 = (const float4*)e;
    float a0 = 0.f, a1 = 0.f, a2 = 0.f, a3 = 0.f;
#pragma unroll
    for (int j = 0; j < HIDDEN / 4; ++j) {
        float4 w = wrow[j];
        float4 h = e4[j];
        a0 += w.x * h.x; a1 += w.y * h.y; a2 += w.z * h.z; a3 += w.w * h.w;
    }
    embW[v * HIDDEN + i] = (a0 + a1) + (a2 + a3);
}

// 1024 blocks x 256 threads (4 waves) -- ONE batch row per block.
// 4-8 blocks co-resident per CU = multiple INDEPENDENT barrier groups: when
// one block's waves stall in their step chain, other blocks issue.
// Transposed recurrence z^T = W_hh * h^T; wave w owns z-cols [32w,32w+32)
// (2 M-tiles). MFMA n-dim (16) aliases the single row 16x: all h reads are
// same-address broadcasts (free); only r16==0 lanes write. Per lane per step:
// 8 MFMA (4 indep 2-chains) + 8 tanh + 2 guarded ds_write_b64 + 1 barrier.
// All K-loop traffic is LDS. Block runs exactly its row's length.
__global__ void __launch_bounds__(256, 4)
rnn_mfma(const int* __restrict__ x, const int* __restrict__ lengths,
         const float* __restrict__ embW, const float* __restrict__ W_hh,
         const float* __restrict__ W_fc, const float* __restrict__ b_fc,
         float* __restrict__ out) {
    const int tid = threadIdx.x;
    const int wave = tid >> 6;   // 0..3
    const int lane = tid & 63;
    const int q = lane >> 4;     // 0..3
    const int r16 = lane & 15;   // MFMA n index (all alias the single row)
    const int c0 = wave * 32;    // wave's z-col base (2 M-tiles)
    const int row = blockIdx.x;

    __shared__ __align__(16) _Float16 Ah[2][ASTRIDE];      // 544 B
    __shared__ __align__(16) _Float16 ew[VOCAB][EWSTRIDE]; // 15840 B
    __shared__ int xs[SEQ];                                // 1024 B
    __shared__ __align__(16) float hfin[HIDDEN];           // 512 B

    // Stage: ew (f32->f16), this row's tokens; zero both h buffers.
    for (int idx = tid; idx < VOCAB * HIDDEN; idx += 256) {
        int v = idx >> 7, c = idx & 127;
        ew[v][c] = (_Float16)embW[idx];
    }
    xs[tid] = x[row * SEQ + tid];
    if (tid < 2 * ASTRIDE / 2) ((int*)Ah)[tid] = 0;  // 272 dwords total; 256 threads
    if (tid < 16) ((int*)Ah)[256 + tid] = 0;

    const int len = lengths[row];  // uniform scalar

    // Static A-frags of W_hh for this wave's 2 M-tiles:
    // A[m=r16][k=kc*32+q*8+j] = W_hh[c0 + 16*nt + r16][kc*32 + q*8 + j].
    f16x8 Wf[2][4];
#pragma unroll
    for (int nt = 0; nt < 2; ++nt) {
        const float* wrow = W_hh + (c0 + 16 * nt + r16) * HIDDEN + q * 8;
#pragma unroll
        for (int kc = 0; kc < 4; ++kc) {
            const float* p = wrow + kc * 32;
#pragma unroll
            for (int j = 0; j < 8; ++j) Wf[nt][kc][j] = (_Float16)p[j];
        }
    }

    __syncthreads();

    // Seed pipeline (all LDS): seed for step t prefetched during step t-1.
    int tok = xs[0];
    f16x4 s0 = *(const f16x4*)&ew[tok][c0 + 4 * q];
    f16x4 s1 = *(const f16x4*)&ew[tok][c0 + 16 + 4 * q];
    int tok1 = xs[1];  // SEQ >= 2 always

    int cur = 0;
    f32x4 cap0 = {0.f, 0.f, 0.f, 0.f}, cap1 = {0.f, 0.f, 0.f, 0.f};

    for (int t = 0; t < len; ++t) {
        // h B-frags: B[k][n] = h[k] (same-address broadcast across all n-lanes).
        const _Float16* hb = &Ah[cur][q * 8];
        f16x8 H0 = *(const f16x8*)(hb + 0);
        f16x8 H1 = *(const f16x8*)(hb + 32);
        f16x8 H2 = *(const f16x8*)(hb + 64);
        f16x8 H3 = *(const f16x8*)(hb + 96);

        // Prefetch seed for t+1 and token for t+2 (LDS only).
        f16x4 sn0 = *(const f16x4*)&ew[tok1][c0 + 4 * q];
        f16x4 sn1 = *(const f16x4*)&ew[tok1][c0 + 16 + 4 * q];
        const int t2 = (t + 2 < SEQ) ? t + 2 : SEQ - 1;
        const int tok2 = xs[t2];

        // 4 independent 2-deep MFMA chains (2 M-tiles x split-K).
        f32x4 a0 = {(float)s0[0], (float)s0[1], (float)s0[2], (float)s0[3]};
        f32x4 a1 = {(float)s1[0], (float)s1[1], (float)s1[2], (float)s1[3]};
        f32x4 d0 = {0.f, 0.f, 0.f, 0.f}, d1 = {0.f, 0.f, 0.f, 0.f};
        a0 = __builtin_amdgcn_mfma_f32_16x16x32_f16(Wf[0][0], H0, a0, 0, 0, 0);
        a1 = __builtin_amdgcn_mfma_f32_16x16x32_f16(Wf[1][0], H0, a1, 0, 0, 0);
        d0 = __builtin_amdgcn_mfma_f32_16x16x32_f16(Wf[0][2], H2, d0, 0, 0, 0);
        d1 = __builtin_amdgcn_mfma_f32_16x16x32_f16(Wf[1][2], H2, d1, 0, 0, 0);
        a0 = __builtin_amdgcn_mfma_f32_16x16x32_f16(Wf[0][1], H1, a0, 0, 0, 0);
        a1 = __builtin_amdgcn_mfma_f32_16x16x32_f16(Wf[1][1], H1, a1, 0, 0, 0);
        d0 = __builtin_amdgcn_mfma_f32_16x16x32_f16(Wf[0][3], H3, d0, 0, 0, 0);
        d1 = __builtin_amdgcn_mfma_f32_16x16x32_f16(Wf[1][3], H3, d1, 0, 0, 0);
        f32x4 z0 = a0 + d0;
        f32x4 z1 = a1 + d1;

        f32x4 th0, th1;
#pragma unroll
        for (int v = 0; v < 4; ++v) {
            th0[v] = fast_tanh(z0[v]);
            th1[v] = fast_tanh(z1[v]);
        }
        if (t + 1 == len) { cap0 = th0; cap1 = th1; }

        uint2 p0, p1;
        p0.x = __builtin_bit_cast(unsigned int, __builtin_amdgcn_cvt_pkrtz(th0[0], th0[1]));
        p0.y = __builtin_bit_cast(unsigned int, __builtin_amdgcn_cvt_pkrtz(th0[2], th0[3]));
        p1.x = __builtin_bit_cast(unsigned int, __builtin_amdgcn_cvt_pkrtz(th1[0], th1[1]));
        p1.y = __builtin_bit_cast(unsigned int, __builtin_amdgcn_cvt_pkrtz(th1[2], th1[3]));

        const int nxt = cur ^ 1;
        if (r16 == 0) {  // one writer per col-quad; aliased lanes hold identical data
            *(uint2*)&Ah[nxt][c0 + 4 * q] = p0;
            *(uint2*)&Ah[nxt][c0 + 16 + 4 * q] = p1;
        }
        __syncthreads();
        cur = nxt;
        s0 = sn0; s1 = sn1;
        tok1 = tok2;
    }

    // Final h (fp32) -> hfin, then FC epilogue.
    if (r16 == 0) {
        *(f32x4*)&hfin[c0 + 4 * q] = cap0;
        *(f32x4*)&hfin[c0 + 16 + 4 * q] = cap1;
    }
    __syncthreads();

    // FC: thread c computes out[row][c] (hfin broadcast-read by all lanes).
    const int c = tid;
    if (c < VOCAB) {
        const float4* hv = (const float4*)hfin;
        const float4* wf = (const float4*)(W_fc + c * HIDDEN);
        float a0 = 0.f, a1 = 0.f, a2 = 0.f, a3 = 0.f;
#pragma unroll
        for (int j = 0; j < HIDDEN / 4; ++j) {
            float4 h = hv[j];
            float4 w = wf[j];
            a0 += h.x * w.x; a1 += h.y * w.y; a2 += h.z * w.z; a3 += h.w * w.w;
        }
        out[row * VOCAB + c] = (a0 + a1) + (a2 + a3) + b_fc[c];
    }
}

extern "C" void kernel_launch(void* const* d_in, const int* in_sizes, int n_in,
                              void* d_out, int out_size, void* d_ws, size_t ws_size,
                              hipStream_t stream) {
    const int* x = (const int*)d_in[0];          // [B, T] int32
    const int* lengths = (const int*)d_in[1];    // [B] int32
    const float* emb = (const float*)d_in[2];    // [V, H]
    const float* W_ih = (const float*)d_in[3];   // [H, H]
    const float* W_hh = (const float*)d_in[4];   // [H, H]
    const float* W_fc = (const float*)d_in[5];   // [V, H]
    const float* b_fc = (const float*)d_in[6];   // [V]
    float* out = (float*)d_out;                  // [B, V]

    float* embW = (float*)d_ws;                  // VOCAB*HIDDEN floats (30 KB)

    rnn_prep_embw<<<VOCAB, HIDDEN, 0, stream>>>(emb, W_ih, embW);
    rnn_mfma<<<BATCH, 256, 0, stream>>>(x, lengths, embW, W_hh, W_fc, b_fc, out);
}

// Round 13
// 164.371 us; speedup vs baseline: 1.6410x; 1.6410x over previous
//
#include <hip/hip_runtime.h>
#include <hip/hip_bf16.h>

#define BATCH 1024
#define SEQ 256
#define HIDDEN 128
#define VOCAB 60
#define ROWS 4             // real batch rows per block (MFMA n-dim aliased 4x)
#define CHUNK 16           // ring-buffer depth in time steps
#define ASTRIDE 144        // f16 per h row: 72 dw == 8 mod 32 -> (8r+4q) all-distinct-ish, max 2-way (free)
#define RSTR 136           // f32 per ring row: 136 == 8 mod 32 -> same property; 544 B keeps 16B align

typedef _Float16 f16x8 __attribute__((ext_vector_type(8)));
typedef _Float16 f16x4 __attribute__((ext_vector_type(4)));
typedef float f32x4 __attribute__((ext_vector_type(4)));

__device__ __forceinline__ float fast_tanh(float x) {
    // tanh(x) = 1 - 2/(exp(2x)+1); exp(2x)=exp2(x*2*log2e). Branch-free, exact +-1 tails.
    float e = __builtin_amdgcn_exp2f(x * 2.8853900817779268f);
    return __builtin_fmaf(-2.0f, __builtin_amdgcn_rcpf(e + 1.0f), 1.0f);
}

// embW[v][i] = sum_j emb[v][j] * W_ih[i][j]  (fp32-exact input-projection table)
__global__ void rnn_prep_embw(const float* __restrict__ emb,
                              const float* __restrict__ W_ih,
                              float* __restrict__ embW) {
    const int v = blockIdx.x;
    const int i = threadIdx.x;
    __shared__ __align__(16) float e[HIDDEN];
    e[i] = emb[v * HIDDEN + i];
    __syncthreads();
    const float4* wrow = (const float4*)(W_ih + i * HIDDEN);
    const float4* e4 = (const float4*)e;
    float a0 = 0.f, a1 = 0.f, a2 = 0.f, a3 = 0.f;
#pragma unroll
    for (int j = 0; j < HIDDEN / 4; ++j) {
        float4 w = wrow[j];
        float4 h = e4[j];
        a0 += w.x * h.x; a1 += w.y * h.y; a2 += w.z * h.z; a3 += w.w * h.w;
    }
    embW[v * HIDDEN + i] = (a0 + a1) + (a2 + a3);
}

// 256 blocks x 512 threads (8 waves, 2/SIMD), 4 batch rows per block.
// Transposed recurrence z^T = W_hh * h^T; wave w owns z-cols [16w,16w+16).
// MFMA n-dim (16) aliases the 4 real rows 4x (broadcast reads are free);
// only r16<4 lanes write h. Every CHUNK steps the block stages the fp32
// embW seeds for the next CHUNK steps into a contiguous LDS ring (global
// gather amortized & wave-pipelined); the in-loop seed is ONE conflict-free
// ds_read_b128 feeding the MFMA C-operand directly. All in-loop traffic is
// conflict-free (<=2-way) LDS.
__global__ void __launch_bounds__(512)
rnn_mfma(const int* __restrict__ x, const int* __restrict__ lengths,
         const float* __restrict__ embW, const float* __restrict__ W_hh,
         const float* __restrict__ W_fc, const float* __restrict__ b_fc,
         float* __restrict__ out) {
    const int tid = threadIdx.x;
    const int wave = tid >> 6;   // 0..7
    const int lane = tid & 63;
    const int q = lane >> 4;     // 0..3
    const int r16 = lane & 15;   // MFMA n index
    const int r4 = r16 & 3;      // real batch row (aliased 4x)
    const int c0 = wave * 16;    // wave's 16 z-cols
    const int b0 = blockIdx.x * ROWS;

    __shared__ __align__(16) float ring[CHUNK][ROWS][RSTR];   // 34816 B
    __shared__ __align__(16) _Float16 Ah[2][ROWS][ASTRIDE];   // 2304 B
    __shared__ int xs[ROWS][SEQ + 1];                         // 4112 B
    __shared__ __align__(16) float hfin[ROWS][HIDDEN];        // 2048 B
    __shared__ int lenbuf[ROWS];

    // Stage tokens + lengths; zero both h buffers.
    for (int idx = tid; idx < ROWS * SEQ; idx += 512) {
        int r = idx >> 8, t = idx & (SEQ - 1);
        xs[r][t] = x[(b0 + r) * SEQ + t];
    }
    if (tid < ROWS) lenbuf[tid] = lengths[b0 + tid];
    for (int idx = tid; idx < (int)(sizeof(Ah) / 4); idx += 512)
        ((int*)Ah)[idx] = 0;

    // Static A-frags of W_hh for this wave's 16-col slice:
    // A[m=r16][k=kc*32+q*8+j] = W_hh[c0 + r16][kc*32 + q*8 + j]. 16 VGPRs.
    f16x8 Wf[4];
    {
        const float* wrow = W_hh + (c0 + r16) * HIDDEN + q * 8;
#pragma unroll
        for (int kc = 0; kc < 4; ++kc) {
            const float* p = wrow + kc * 32;
#pragma unroll
            for (int j = 0; j < 8; ++j) Wf[kc][j] = (_Float16)p[j];
        }
    }

    __syncthreads();  // xs / lenbuf / Ah visible

    const int mylen = lenbuf[r4];
    int lenmax = 0;
#pragma unroll
    for (int r = 0; r < ROWS; ++r) lenmax = max(lenmax, lenbuf[r]);

    int cur = 0;
    f32x4 cap = {0.f, 0.f, 0.f, 0.f};

    for (int t0 = 0; t0 < lenmax; t0 += CHUNK) {
        // ---- Stage seeds for steps [t0, t0+CHUNK) : fp32 global -> ring ----
        // 2048 float4 moves, 4 per thread. idx -> (tp, r, c4).
#pragma unroll
        for (int k = 0; k < 4; ++k) {
            int idx = tid + k * 512;
            int c4 = idx & 31;
            int r = (idx >> 5) & 3;
            int tp = idx >> 7;                  // 0..15
            int tok = xs[r][t0 + tp];           // t0+tp <= 255 always
            f32x4 v = *(const f32x4*)(embW + tok * HIDDEN + c4 * 4);
            *(f32x4*)&ring[tp][r][c4 * 4] = v;
        }
        __syncthreads();

        const int tend = (lenmax - t0 < CHUNK) ? lenmax - t0 : CHUNK;
        for (int tt = 0; tt < tend; ++tt) {
            // h B-frags: B[k][n=r16] = h[r4][k] (4-way broadcast, conflict-free).
            const _Float16* hb = &Ah[cur][r4][q * 8];
            f16x8 H0 = *(const f16x8*)(hb + 0);
            f16x8 H1 = *(const f16x8*)(hb + 32);
            f16x8 H2 = *(const f16x8*)(hb + 64);
            f16x8 H3 = *(const f16x8*)(hb + 96);

            // Seed: one conflict-free b128 from the ring, feeds C directly.
            f32x4 a = *(const f32x4*)&ring[tt][r4][c0 + 4 * q];
            f32x4 d = {0.f, 0.f, 0.f, 0.f};
            a = __builtin_amdgcn_mfma_f32_16x16x32_f16(Wf[0], H0, a, 0, 0, 0);
            d = __builtin_amdgcn_mfma_f32_16x16x32_f16(Wf[2], H2, d, 0, 0, 0);
            a = __builtin_amdgcn_mfma_f32_16x16x32_f16(Wf[1], H1, a, 0, 0, 0);
            d = __builtin_amdgcn_mfma_f32_16x16x32_f16(Wf[3], H3, d, 0, 0, 0);
            f32x4 z = a + d;

            f32x4 th;
            th[0] = fast_tanh(z[0]);
            th[1] = fast_tanh(z[1]);
            th[2] = fast_tanh(z[2]);
            th[3] = fast_tanh(z[3]);
            if (t0 + tt + 1 == mylen) cap = th;

            uint2 pk;
            pk.x = __builtin_bit_cast(unsigned int, __builtin_amdgcn_cvt_pkrtz(th[0], th[1]));
            pk.y = __builtin_bit_cast(unsigned int, __builtin_amdgcn_cvt_pkrtz(th[2], th[3]));

            const int nxt = cur ^ 1;
            if (r16 < ROWS)  // one writer per (row, col-quad)
                *(uint2*)&Ah[nxt][r16][c0 + 4 * q] = pk;
            __syncthreads();
            cur = nxt;
        }
    }

    // Final h (fp32 captures) -> hfin, then FC epilogue.
    if (r16 < ROWS)
        *(f32x4*)&hfin[r16][c0 + 4 * q] = cap;
    __syncthreads();

    // FC: thread (r, c) computes out[b0+r][c].  512 = 4 rows x 128 slots.
    const int r = tid >> 7;      // 0..3
    const int c = tid & 127;     // 0..127
    if (c < VOCAB) {
        const float4* hv = (const float4*)hfin[r];
        const float4* wf = (const float4*)(W_fc + c * HIDDEN);
        float a0 = 0.f, a1 = 0.f, a2 = 0.f, a3 = 0.f;
#pragma unroll
        for (int j = 0; j < HIDDEN / 4; ++j) {
            float4 h = hv[j];
            float4 w = wf[j];
            a0 += h.x * w.x; a1 += h.y * w.y; a2 += h.z * w.z; a3 += h.w * w.w;
        }
        out[(b0 + r) * VOCAB + c] = (a0 + a1) + (a2 + a3) + b_fc[c];
    }
}

extern "C" void kernel_launch(void* const* d_in, const int* in_sizes, int n_in,
                              void* d_out, int out_size, void* d_ws, size_t ws_size,
                              hipStream_t stream) {
    const int* x = (const int*)d_in[0];          // [B, T] int32
    const int* lengths = (const int*)d_in[1];    // [B] int32
    const float* emb = (const float*)d_in[2];    // [V, H]
    const float* W_ih = (const float*)d_in[3];   // [H, H]
    const float* W_hh = (const float*)d_in[4];   // [H, H]
    const float* W_fc = (const float*)d_in[5];   // [V, H]
    const float* b_fc = (const float*)d_in[6];   // [V]
    float* out = (float*)d_out;                  // [B, V]

    float* embW = (float*)d_ws;                  // VOCAB*HIDDEN floats (30 KB)

    rnn_prep_embw<<<VOCAB, HIDDEN, 0, stream>>>(emb, W_ih, embW);
    rnn_mfma<<<BATCH / ROWS, 512, 0, stream>>>(x, lengths, embW, W_hh, W_fc, b_fc, out);
}

// Round 14
// 161.341 us; speedup vs baseline: 1.6719x; 1.0188x over previous
//
#include <hip/hip_runtime.h>
#include <hip/hip_bf16.h>

#define BATCH 1024
#define SEQ 256
#define HIDDEN 128
#define VOCAB 60
#define ROWS 4             // real batch rows per block (MFMA n-dim aliased 4x)
#define CHUNK 16           // ring-buffer depth in time steps
#define ASTRIDE 144        // f16 per h row: 72 dw == 8 mod 32 -> max 2-way (free)
#define RSTR 136           // f32 per ring row: 136 == 8 mod 32 -> conflict-free b128 pattern

typedef _Float16 f16x8 __attribute__((ext_vector_type(8)));
typedef _Float16 f16x4 __attribute__((ext_vector_type(4)));
typedef float f32x4 __attribute__((ext_vector_type(4)));

__device__ __forceinline__ float fast_tanh(float x) {
    // tanh(x) = 1 - 2/(exp(2x)+1); exp(2x)=exp2(x*2*log2e). Branch-free, exact +-1 tails.
    float e = __builtin_amdgcn_exp2f(x * 2.8853900817779268f);
    return __builtin_fmaf(-2.0f, __builtin_amdgcn_rcpf(e + 1.0f), 1.0f);
}

// embW[v][i] = sum_j emb[v][j] * W_ih[i][j]  (fp32-exact input-projection table)
__global__ void rnn_prep_embw(const float* __restrict__ emb,
                              const float* __restrict__ W_ih,
                              float* __restrict__ embW) {
    const int v = blockIdx.x;
    const int i = threadIdx.x;
    __shared__ __align__(16) float e[HIDDEN];
    e[i] = emb[v * HIDDEN + i];
    __syncthreads();
    const float4* wrow = (const float4*)(W_ih + i * HIDDEN);
    const float4* e4 = (const float4*)e;
    float a0 = 0.f, a1 = 0.f, a2 = 0.f, a3 = 0.f;
#pragma unroll
    for (int j = 0; j < HIDDEN / 4; ++j) {
        float4 w = wrow[j];
        float4 h = e4[j];
        a0 += w.x * h.x; a1 += w.y * h.y; a2 += w.z * h.z; a3 += w.w * h.w;
    }
    embW[v * HIDDEN + i] = (a0 + a1) + (a2 + a3);
}

// 256 blocks x 512 threads (8 waves, 2/SIMD), 4 batch rows per block.
// Transposed recurrence z^T = W_hh * h^T; wave w owns z-cols [16w,16w+16).
// MFMA n-dim (16) aliases the 4 real rows 4x (broadcast reads, free); only
// r16<4 lanes write h. Seed staging is SOFTWARE-PIPELINED: global embW loads
// for chunk k+1 are issued into registers right after chunk k's boundary
// barrier (they drain at the next per-step barrier, ~1000 cyc later — L2
// latency fully hidden); the boundary itself only writes regs->ring.
// All in-loop traffic is conflict-free LDS.
__global__ void __launch_bounds__(512)
rnn_mfma(const int* __restrict__ x, const int* __restrict__ lengths,
         const float* __restrict__ embW, const float* __restrict__ W_hh,
         const float* __restrict__ W_fc, const float* __restrict__ b_fc,
         float* __restrict__ out) {
    const int tid = threadIdx.x;
    const int wave = tid >> 6;   // 0..7
    const int lane = tid & 63;
    const int q = lane >> 4;     // 0..3
    const int r16 = lane & 15;   // MFMA n index
    const int r4 = r16 & 3;      // real batch row (aliased 4x)
    const int c0 = wave * 16;    // wave's 16 z-cols
    const int b0 = blockIdx.x * ROWS;

    __shared__ __align__(16) float ring[CHUNK][ROWS][RSTR];   // 34816 B
    __shared__ __align__(16) _Float16 Ah[2][ROWS][ASTRIDE];   // 2304 B
    __shared__ int xs[ROWS][SEQ + 1];                         // 4112 B
    __shared__ __align__(16) float hfin[ROWS][HIDDEN];        // 2048 B
    __shared__ int lenbuf[ROWS];

    // Stage tokens + lengths; zero both h buffers.
    for (int idx = tid; idx < ROWS * SEQ; idx += 512) {
        int r = idx >> 8, t = idx & (SEQ - 1);
        xs[r][t] = x[(b0 + r) * SEQ + t];
    }
    if (tid < ROWS) lenbuf[tid] = lengths[b0 + tid];
    for (int idx = tid; idx < (int)(sizeof(Ah) / 4); idx += 512)
        ((int*)Ah)[idx] = 0;

    // Static A-frags of W_hh for this wave's 16-col slice:
    // A[m=r16][k=kc*32+q*8+j] = W_hh[c0 + r16][kc*32 + q*8 + j]. 16 VGPRs.
    f16x8 Wf[4];
    {
        const float* wrow = W_hh + (c0 + r16) * HIDDEN + q * 8;
#pragma unroll
        for (int kc = 0; kc < 4; ++kc) {
            const float* p = wrow + kc * 32;
#pragma unroll
            for (int j = 0; j < 8; ++j) Wf[kc][j] = (_Float16)p[j];
        }
    }

    __syncthreads();  // xs / lenbuf / Ah visible

    const int mylen = lenbuf[r4];
    int lenmax = 0;
#pragma unroll
    for (int r = 0; r < ROWS; ++r) lenmax = max(lenmax, lenbuf[r]);

    // Staging-thread mapping: idx = tid + 512k -> (tp, r, c4).
    const int s_c4 = tid & 31;
    const int s_r = (tid >> 5) & 3;
    const int s_tp = tid >> 7;   // 0..3, +4 per k

    // Prefetch chunk 0 seeds into registers.
    f32x4 rg[4];
#pragma unroll
    for (int k = 0; k < 4; ++k) {
        int tp = s_tp + 4 * k;
        int tok = xs[s_r][tp];
        rg[k] = *(const f32x4*)(embW + tok * HIDDEN + s_c4 * 4);
    }

    int cur = 0;
    f32x4 cap = {0.f, 0.f, 0.f, 0.f};

    for (int t0 = 0; t0 < lenmax; t0 += CHUNK) {
        // Boundary: staged regs -> ring (LDS only, cheap), then barrier.
#pragma unroll
        for (int k = 0; k < 4; ++k)
            *(f32x4*)&ring[s_tp + 4 * k][s_r][s_c4 * 4] = rg[k];
        __syncthreads();

        // Issue next chunk's global loads now; they complete during the
        // first couple of steps and drain harmlessly at a step barrier.
        if (t0 + CHUNK < lenmax) {
            const int t0n = t0 + CHUNK;
#pragma unroll
            for (int k = 0; k < 4; ++k) {
                int tp = s_tp + 4 * k;
                int tok = xs[s_r][t0n + tp];
                rg[k] = *(const f32x4*)(embW + tok * HIDDEN + s_c4 * 4);
            }
        }

        const int tend = (lenmax - t0 < CHUNK) ? lenmax - t0 : CHUNK;
        for (int tt = 0; tt < tend; ++tt) {
            // h B-frags: B[k][n=r16] = h[r4][k] (4-way broadcast, conflict-free).
            const _Float16* hb = &Ah[cur][r4][q * 8];
            f16x8 H0 = *(const f16x8*)(hb + 0);
            f16x8 H1 = *(const f16x8*)(hb + 32);
            f16x8 H2 = *(const f16x8*)(hb + 64);
            f16x8 H3 = *(const f16x8*)(hb + 96);

            // Seed: one conflict-free b128 from the ring, feeds C directly.
            f32x4 a = *(const f32x4*)&ring[tt][r4][c0 + 4 * q];
            f32x4 d = {0.f, 0.f, 0.f, 0.f};
            a = __builtin_amdgcn_mfma_f32_16x16x32_f16(Wf[0], H0, a, 0, 0, 0);
            d = __builtin_amdgcn_mfma_f32_16x16x32_f16(Wf[2], H2, d, 0, 0, 0);
            a = __builtin_amdgcn_mfma_f32_16x16x32_f16(Wf[1], H1, a, 0, 0, 0);
            d = __builtin_amdgcn_mfma_f32_16x16x32_f16(Wf[3], H3, d, 0, 0, 0);
            f32x4 z = a + d;

            f32x4 th;
            th[0] = fast_tanh(z[0]);
            th[1] = fast_tanh(z[1]);
            th[2] = fast_tanh(z[2]);
            th[3] = fast_tanh(z[3]);

            uint2 pk;
            pk.x = __builtin_bit_cast(unsigned int, __builtin_amdgcn_cvt_pkrtz(th[0], th[1]));
            pk.y = __builtin_bit_cast(unsigned int, __builtin_amdgcn_cvt_pkrtz(th[2], th[3]));

            const int nxt = cur ^ 1;
            if (r16 < ROWS)  // one writer per (row, col-quad)
                *(uint2*)&Ah[nxt][r16][c0 + 4 * q] = pk;
            // Capture off the critical path (after the write).
            if (t0 + tt + 1 == mylen) cap = th;
            __syncthreads();
            cur = nxt;
        }
    }

    // Final h (fp32 captures) -> hfin, then FC epilogue.
    if (r16 < ROWS)
        *(f32x4*)&hfin[r16][c0 + 4 * q] = cap;
    __syncthreads();

    // FC: thread (r, c) computes out[b0+r][c].  512 = 4 rows x 128 slots.
    const int r = tid >> 7;      // 0..3
    const int c = tid & 127;     // 0..127
    if (c < VOCAB) {
        const float4* hv = (const float4*)hfin[r];
        const float4* wf = (const float4*)(W_fc + c * HIDDEN);
        float a0 = 0.f, a1 = 0.f, a2 = 0.f, a3 = 0.f;
#pragma unroll
        for (int j = 0; j < HIDDEN / 4; ++j) {
            float4 h = hv[j];
            float4 w = wf[j];
            a0 += h.x * w.x; a1 += h.y * w.y; a2 += h.z * w.z; a3 += h.w * w.w;
        }
        out[(b0 + r) * VOCAB + c] = (a0 + a1) + (a2 + a3) + b_fc[c];
    }
}

extern "C" void kernel_launch(void* const* d_in, const int* in_sizes, int n_in,
                              void* d_out, int out_size, void* d_ws, size_t ws_size,
                              hipStream_t stream) {
    const int* x = (const int*)d_in[0];          // [B, T] int32
    const int* lengths = (const int*)d_in[1];    // [B] int32
    const float* emb = (const float*)d_in[2];    // [V, H]
    const float* W_ih = (const float*)d_in[3];   // [H, H]
    const float* W_hh = (const float*)d_in[4];   // [H, H]
    const float* W_fc = (const float*)d_in[5];   // [V, H]
    const float* b_fc = (const float*)d_in[6];   // [V]
    float* out = (float*)d_out;                  // [B, V]

    float* embW = (float*)d_ws;                  // VOCAB*HIDDEN floats (30 KB)

    rnn_prep_embw<<<VOCAB, HIDDEN, 0, stream>>>(emb, W_ih, embW);
    rnn_mfma<<<BATCH / ROWS, 512, 0, stream>>>(x, lengths, embW, W_hh, W_fc, b_fc, out);
}